// Round 3
// 2254.768 us; speedup vs baseline: 1.5482x; 1.5482x over previous
//
#include <hip/hip_runtime.h>
#include <hip/hip_bf16.h>
#include <math.h>

#define Dm   1024
#define Hn   16
#define HDm  64
#define Lm   2048
#define Wm   256
#define Im   3280
#define Vm   32000
#define NLAYER 4
#define EPSf 1e-5f

typedef unsigned short ushort;
typedef __attribute__((ext_vector_type(8))) short bf16x8;
typedef __attribute__((ext_vector_type(4))) float f32x4;

static __device__ __forceinline__ float clamp10k(float x) {
    return fminf(fmaxf(x, -10000.0f), 10000.0f);
}

static __device__ __forceinline__ ushort f2bf(float f) {
    __hip_bfloat16 h = __float2bfloat16(f);
    return *reinterpret_cast<ushort*>(&h);
}

// async global->LDS, 16 bytes per lane; LDS dest = wave-uniform base + lane*16
static __device__ __forceinline__ void gload16(const ushort* g, ushort* l) {
    __builtin_amdgcn_global_load_lds(
        (const __attribute__((address_space(1))) void*)(const void*)g,
        (__attribute__((address_space(3))) void*)(void*)l, 16, 0, 0);
}

// ---------------- embedding gather ----------------
__global__ __launch_bounds__(256) void embed_k(const int* __restrict__ tok,
                                               const float* __restrict__ ew,
                                               float* __restrict__ x) {
    int i = blockIdx.x;
    int t = tok[i];
    const float4* src = (const float4*)(ew + (size_t)t * Dm);
    float4* dst = (float4*)(x + (size_t)i * Dm);
    dst[threadIdx.x] = src[threadIdx.x];
}

// ---------------- RMSNorm over D=1024, bf16 output ----------------
__global__ __launch_bounds__(256) void rmsnorm_row(const float* __restrict__ x,
                                                   const float* __restrict__ w,
                                                   ushort* __restrict__ out) {
    __shared__ float red[256];
    int row = blockIdx.x, tid = threadIdx.x;
    float4 vx = ((const float4*)(x + (size_t)row * Dm))[tid];
    vx.x = clamp10k(vx.x); vx.y = clamp10k(vx.y);
    vx.z = clamp10k(vx.z); vx.w = clamp10k(vx.w);
    float ss = vx.x * vx.x + vx.y * vx.y + vx.z * vx.z + vx.w * vx.w;
    red[tid] = ss;
    __syncthreads();
    for (int s = 128; s > 0; s >>= 1) {
        if (tid < s) red[tid] += red[tid + s];
        __syncthreads();
    }
    float mean = red[0] * (1.0f / Dm);
    float inv = 1.0f / sqrtf(fmaxf(mean, EPSf) + EPSf);
    float4 vw = ((const float4*)w)[tid];
    float o0 = vx.x * inv * vw.x;
    float o1 = vx.y * inv * vw.y;
    float o2 = vx.z * inv * vw.z;
    float o3 = vx.w * inv * vw.w;
    if (!isfinite(o0)) o0 = 0.0f;
    if (!isfinite(o1)) o1 = 0.0f;
    if (!isfinite(o2)) o2 = 0.0f;
    if (!isfinite(o3)) o3 = 0.0f;
    ushort4 o;
    o.x = f2bf(o0); o.y = f2bf(o1); o.z = f2bf(o2); o.w = f2bf(o3);
    ((ushort4*)(out + (size_t)row * Dm))[tid] = o;
}

// ---------------- per-head RMSNorm over hd=64 -> bf16 [h][L][64] ----------------
// input qk fp32 [L][H*64]: row r = i*16 + h. One wave per row, 4 rows/block.
__global__ __launch_bounds__(256) void rmsnorm_head_bf16(const float* __restrict__ qk,
                                                         const float* __restrict__ w,
                                                         ushort* __restrict__ out) {
    int wave = threadIdx.x >> 6, lane = threadIdx.x & 63;
    int r = blockIdx.x * 4 + wave;
    int i = r >> 4, h = r & 15;
    float xv = clamp10k(qk[(size_t)r * HDm + lane]);
    float ss = xv * xv;
#pragma unroll
    for (int off = 32; off >= 1; off >>= 1) ss += __shfl_xor(ss, off, 64);
    float mean = ss * (1.0f / HDm);
    float inv = 1.0f / sqrtf(fmaxf(mean, EPSf) + EPSf);
    float o = xv * inv * w[lane];
    if (!isfinite(o)) o = 0.0f;
    out[((size_t)h * Lm + i) * HDm + lane] = f2bf(o);
}

// ---------------- V transpose: vb fp32 [L][D] -> vt bf16 [h][64][L] ----------------
__global__ __launch_bounds__(256) void vtrans_k(const float* __restrict__ vb,
                                                ushort* __restrict__ vt) {
    __shared__ ushort tile[64 * 72];   // [d][i], padded stride
    int i0 = blockIdx.x * 64, h = blockIdx.y;
    int t = threadIdx.x;
    int r = t >> 2, q4 = t & 3;        // r = i-row 0..63
    const float4* src = (const float4*)(vb + (size_t)(i0 + r) * Dm + h * HDm);
#pragma unroll
    for (int k = 0; k < 4; ++k) {
        int c4 = q4 + k * 4;           // float4 index 0..15
        float4 v = src[c4];
        int c = c4 * 4;
        tile[(c + 0) * 72 + r] = f2bf(v.x);
        tile[(c + 1) * 72 + r] = f2bf(v.y);
        tile[(c + 2) * 72 + r] = f2bf(v.z);
        tile[(c + 3) * 72 + r] = f2bf(v.w);
    }
    __syncthreads();
    int d = t >> 2, ch = t & 3;
    uint4 a = *(const uint4*)&tile[d * 72 + ch * 16];
    uint4 b = *(const uint4*)&tile[d * 72 + ch * 16 + 8];
    ushort* dst = vt + ((size_t)(h * HDm + d)) * Lm + i0 + ch * 16;
    *(uint4*)dst = a;
    *(uint4*)(dst + 8) = b;
}

// ---------------- MFMA sliding-window flash attention ----------------
// qh,kh: bf16 [h][L][64]; vt: bf16 [h][64][L]; out: bf16 [L][D]
// block: 64 queries x 1 head; 4 waves x 16 q-rows; KV tiles of 32 keys.
// S^T = K*Q^T via mfma(A=K rows, B=Q rows): lane holds col=q(l15), row=key(quad*4+reg)
__global__ __launch_bounds__(256) void attn_mfma(const ushort* __restrict__ qh,
                                                 const ushort* __restrict__ kh,
                                                 const ushort* __restrict__ vt,
                                                 ushort* __restrict__ out) {
    __shared__ ushort Ks[32 * 72];     // [key][feat], padded
    __shared__ ushort Vs[64 * 40];     // [feat][key], padded
    __shared__ ushort Pl[4][16 * 40];  // per-wave P [q][key], padded

    const int tid  = threadIdx.x;
    const int wave = tid >> 6;
    const int lane = tid & 63;
    const int l15  = lane & 15;
    const int quad = lane >> 4;
    const int h    = blockIdx.y;
    const int q0   = blockIdx.x * 64;
    const int qw   = q0 + wave * 16;
    const int qmy  = qw + l15;

    // Q fragments hoisted (B operand: lane holds Q[q=l15][feat=quad*8+j (+32)])
    const ushort* qbase = qh + ((size_t)h * Lm + qw + l15) * HDm;
    bf16x8 qf0 = *(const bf16x8*)(qbase + quad * 8);
    bf16x8 qf1 = *(const bf16x8*)(qbase + 32 + quad * 8);

    f32x4 o0 = {0.f, 0.f, 0.f, 0.f}, o1 = o0, o2 = o0, o3 = o0;
    // m floor at -1e4: legit scores bounded ~|512|, so max(m, rm) never binds on
    // real data, and fully-masked tiles give p = exp(-1e30 + 1e4) = 0 exactly.
    float m = -1e4f, lsum = 0.0f;

    const int krow = tid >> 3, kch = tid & 7;
    const int vrow = tid >> 2, vch = tid & 3;
    const ushort* kg = kh + ((size_t)h * Lm + krow) * HDm + kch * 8;
    const ushort* vg = vt + ((size_t)(h * HDm + vrow)) * Lm + vch * 8;

    int tlo = q0 - 256; if (tlo < 0) tlo = 0;

    for (int t0 = tlo; t0 < q0 + 64; t0 += 32) {
        __syncthreads();
        *(uint4*)&Ks[krow * 72 + kch * 8] = *(const uint4*)(kg + (size_t)t0 * HDm);
        *(uint4*)&Vs[vrow * 40 + vch * 8] = *(const uint4*)(vg + t0);
        __syncthreads();

        if (t0 <= qw + 15 && t0 + 31 >= qw - 255) {
            bf16x8 k00 = *(const bf16x8*)&Ks[l15 * 72 + quad * 8];
            bf16x8 k01 = *(const bf16x8*)&Ks[l15 * 72 + 32 + quad * 8];
            bf16x8 k10 = *(const bf16x8*)&Ks[(l15 + 16) * 72 + quad * 8];
            bf16x8 k11 = *(const bf16x8*)&Ks[(l15 + 16) * 72 + 32 + quad * 8];
            f32x4 s0 = {0.f, 0.f, 0.f, 0.f}, s1 = s0;
            s0 = __builtin_amdgcn_mfma_f32_16x16x32_bf16(k00, qf0, s0, 0, 0, 0);
            s0 = __builtin_amdgcn_mfma_f32_16x16x32_bf16(k01, qf1, s0, 0, 0, 0);
            s1 = __builtin_amdgcn_mfma_f32_16x16x32_bf16(k10, qf0, s1, 0, 0, 0);
            s1 = __builtin_amdgcn_mfma_f32_16x16x32_bf16(k11, qf1, s1, 0, 0, 0);

            float sv[8];
            bool full = (t0 + 31 <= qw) && (t0 >= qw - 240);
            int jb = t0 + quad * 4;
            if (full) {
#pragma unroll
                for (int r = 0; r < 4; ++r) {
                    sv[r]     = s0[r] * 0.125f;
                    sv[r + 4] = s1[r] * 0.125f;
                }
            } else {
#pragma unroll
                for (int r = 0; r < 4; ++r) {
                    int ja = jb + r, jc = jb + 16 + r;
                    sv[r]     = (ja <= qmy && ja >= qmy - 255) ? s0[r] * 0.125f : -1e30f;
                    sv[r + 4] = (jc <= qmy && jc >= qmy - 255) ? s1[r] * 0.125f : -1e30f;
                }
            }

            float rm = sv[0];
#pragma unroll
            for (int r = 1; r < 8; ++r) rm = fmaxf(rm, sv[r]);
            rm = fmaxf(rm, __shfl_xor(rm, 16));
            rm = fmaxf(rm, __shfl_xor(rm, 32));
            float mn = fmaxf(m, rm);
            float alpha = __expf(m - mn);
            float p[8], ps = 0.f;
#pragma unroll
            for (int r = 0; r < 8; ++r) { p[r] = __expf(sv[r] - mn); ps += p[r]; }
            ps += __shfl_xor(ps, 16);
            ps += __shfl_xor(ps, 32);
            lsum = lsum * alpha + ps;
            m = mn;

            ushort4 pk0, pk1;
            pk0.x = f2bf(p[0]); pk0.y = f2bf(p[1]); pk0.z = f2bf(p[2]); pk0.w = f2bf(p[3]);
            pk1.x = f2bf(p[4]); pk1.y = f2bf(p[5]); pk1.z = f2bf(p[6]); pk1.w = f2bf(p[7]);
            *(ushort4*)&Pl[wave][l15 * 40 + quad * 4]      = pk0;
            *(ushort4*)&Pl[wave][l15 * 40 + 16 + quad * 4] = pk1;
            asm volatile("s_waitcnt lgkmcnt(0)" ::: "memory");
            bf16x8 pa  = *(const bf16x8*)&Pl[wave][l15 * 40 + quad * 8];
            bf16x8 vf0 = *(const bf16x8*)&Vs[l15 * 40 + quad * 8];
            bf16x8 vf1 = *(const bf16x8*)&Vs[(l15 + 16) * 40 + quad * 8];
            bf16x8 vf2 = *(const bf16x8*)&Vs[(l15 + 32) * 40 + quad * 8];
            bf16x8 vf3 = *(const bf16x8*)&Vs[(l15 + 48) * 40 + quad * 8];

            float a0 = __shfl(alpha, quad * 4 + 0);
            float a1 = __shfl(alpha, quad * 4 + 1);
            float a2 = __shfl(alpha, quad * 4 + 2);
            float a3 = __shfl(alpha, quad * 4 + 3);
            o0[0] *= a0; o0[1] *= a1; o0[2] *= a2; o0[3] *= a3;
            o1[0] *= a0; o1[1] *= a1; o1[2] *= a2; o1[3] *= a3;
            o2[0] *= a0; o2[1] *= a1; o2[2] *= a2; o2[3] *= a3;
            o3[0] *= a0; o3[1] *= a1; o3[2] *= a2; o3[3] *= a3;

            o0 = __builtin_amdgcn_mfma_f32_16x16x32_bf16(pa, vf0, o0, 0, 0, 0);
            o1 = __builtin_amdgcn_mfma_f32_16x16x32_bf16(pa, vf1, o1, 0, 0, 0);
            o2 = __builtin_amdgcn_mfma_f32_16x16x32_bf16(pa, vf2, o2, 0, 0, 0);
            o3 = __builtin_amdgcn_mfma_f32_16x16x32_bf16(pa, vf3, o3, 0, 0, 0);
        }
    }

    float linv = 1.0f / lsum;
    ushort* ob = out + (size_t)(qw + quad * 4) * Dm + h * HDm + l15;
#pragma unroll
    for (int r = 0; r < 4; ++r) {
        float li = __shfl(linv, quad * 4 + r);
        size_t off = (size_t)r * Dm;
        ob[off]      = f2bf(o0[r] * li);
        ob[off + 16] = f2bf(o1[r] * li);
        ob[off + 32] = f2bf(o2[r] * li);
        ob[off + 48] = f2bf(o3[r] * li);
    }
}

// ---------------- weight fp32 -> bf16 with zero padding to Np x Kp ----------------
__global__ __launch_bounds__(256) void convert_w(const float* __restrict__ src,
                                                 ushort* __restrict__ dst,
                                                 int N, int K, int Kp) {
    int n = blockIdx.y;
    int k = blockIdx.x * 256 + threadIdx.x;
    if (k >= Kp) return;
    float v = 0.0f;
    if (n < N && k < K) v = src[(size_t)n * K + k];
    dst[(size_t)n * Kp + k] = f2bf(v);
}

// ---------------- bf16 MFMA GEMM: C(2048 x N) = A(2048 x K) @ Wb(Npad x K)^T + bias ---
// K = padded K (mult of 32); tile 128x128, 4 waves each 64x64 of 16x16x32 MFMAs.
__global__ __launch_bounds__(256) void gemm_bf16(const ushort* __restrict__ A,
                                                 const ushort* __restrict__ Wb,
                                                 const float* __restrict__ bias,
                                                 float* __restrict__ C,
                                                 int K, int N, int ldc, int act) {
    __shared__ ushort As[128 * 32];
    __shared__ ushort Bs[128 * 32];
    const int tid = threadIdx.x;
    const int wave = tid >> 6;
    const int lane = tid & 63;
    const int lane15 = lane & 15;
    const int quad = lane >> 4;
    const int rowBlk = blockIdx.y * 128;
    const int colBlk = blockIdx.x * 128;
    const int wm = (wave >> 1) * 64;
    const int wn = (wave & 1) * 64;

    const int srow = lane >> 2;          // 0..15 within 16-row group
    const int scol = (lane & 3) * 8;     // bf16 col offset

    const ushort* aSrc0 = A + (size_t)(rowBlk + wave * 32 + srow) * K + scol;
    const ushort* bSrc0 = Wb + (size_t)(colBlk + wave * 32 + srow) * K + scol;
    ushort* aDst0 = &As[(wave * 32) * 32];
    ushort* aDst1 = &As[(wave * 32 + 16) * 32];
    ushort* bDst0 = &Bs[(wave * 32) * 32];
    ushort* bDst1 = &Bs[(wave * 32 + 16) * 32];

    f32x4 acc[4][4];
#pragma unroll
    for (int i = 0; i < 4; ++i)
#pragma unroll
        for (int j = 0; j < 4; ++j) acc[i][j] = (f32x4){0.f, 0.f, 0.f, 0.f};

    for (int k0 = 0; k0 < K; k0 += 32) {
        __syncthreads();   // previous iteration's reads complete
        gload16(aSrc0 + k0, aDst0);
        gload16(aSrc0 + k0 + (size_t)16 * K, aDst1);
        gload16(bSrc0 + k0, bDst0);
        gload16(bSrc0 + k0 + (size_t)16 * K, bDst1);
        __syncthreads();   // staging complete

        bf16x8 a[4], b[4];
#pragma unroll
        for (int im = 0; im < 4; ++im)
            a[im] = *(const bf16x8*)&As[(wm + im * 16 + lane15) * 32 + quad * 8];
#pragma unroll
        for (int in = 0; in < 4; ++in)
            b[in] = *(const bf16x8*)&Bs[(wn + in * 16 + lane15) * 32 + quad * 8];
#pragma unroll
        for (int im = 0; im < 4; ++im)
#pragma unroll
            for (int in = 0; in < 4; ++in)
                acc[im][in] = __builtin_amdgcn_mfma_f32_16x16x32_bf16(
                    a[im], b[in], acc[im][in], 0, 0, 0);
    }

#pragma unroll
    for (int im = 0; im < 4; ++im) {
        int r0 = rowBlk + wm + im * 16 + quad * 4;
#pragma unroll
        for (int in = 0; in < 4; ++in) {
            int c = colBlk + wn + in * 16 + lane15;
            if (c < N) {
                float bia = bias[c];
#pragma unroll
                for (int reg = 0; reg < 4; ++reg) {
                    float v = acc[im][in][reg] + bia;
                    if (act) v = fminf(fmaxf(v, -50.0f), 50.0f);
                    C[(size_t)(r0 + reg) * ldc + c] = v;
                }
            }
        }
    }
}

// ---------------- elementwise: x += t ----------------
__global__ __launch_bounds__(256) void add_k(float* __restrict__ x,
                                             const float* __restrict__ t, int n4) {
    int i = blockIdx.x * 256 + threadIdx.x;
    if (i < n4) {
        float4 a = ((const float4*)x)[i];
        float4 b = ((const float4*)t)[i];
        a.x += b.x; a.y += b.y; a.z += b.z; a.w += b.w;
        ((float4*)x)[i] = a;
    }
}

// ---------------- swiglu: z1b(2048 x 3296 bf16) = silu(z1)*z3, zero-padded ----------
__global__ __launch_bounds__(256) void swiglu_k(const float* __restrict__ z1,
                                                const float* __restrict__ z3,
                                                ushort* __restrict__ z1b) {
    int row = blockIdx.x, tid = threadIdx.x;
    const float* a = z1 + (size_t)row * Im;
    const float* b = z3 + (size_t)row * Im;
    ushort* o = z1b + (size_t)row * 3296;
    for (int c = tid; c < 3296; c += 256) {
        float v = 0.0f;
        if (c < Im) {
            float x = a[c];
            v = x / (1.0f + expf(-x)) * b[c];
        }
        o[c] = f2bf(v);
    }
}

extern "C" void kernel_launch(void* const* d_in, const int* in_sizes, int n_in,
                              void* d_out, int out_size, void* d_ws, size_t ws_size,
                              hipStream_t stream) {
    const int*   tokens  = (const int*)  d_in[0];
    const float* embed_w = (const float*)d_in[1];
    const float* ln1_w   = (const float*)d_in[2];
    const float* ln2_w   = (const float*)d_in[3];
    const float* wq_w    = (const float*)d_in[4];
    const float* wq_b    = (const float*)d_in[5];
    const float* wk_w    = (const float*)d_in[6];
    const float* wk_b    = (const float*)d_in[7];
    const float* wv_w    = (const float*)d_in[8];
    const float* wv_b    = (const float*)d_in[9];
    const float* wo_w    = (const float*)d_in[10];
    const float* wo_b    = (const float*)d_in[11];
    const float* qn_w    = (const float*)d_in[12];
    const float* kn_w    = (const float*)d_in[13];
    const float* w1_w    = (const float*)d_in[14];
    const float* w1_b    = (const float*)d_in[15];
    const float* w2_w    = (const float*)d_in[16];
    const float* w2_b    = (const float*)d_in[17];
    const float* w3_w    = (const float*)d_in[18];
    const float* w3_b    = (const float*)d_in[19];
    const float* lnf_w   = (const float*)d_in[20];
    const float* lm_w    = (const float*)d_in[21];
    const float* lm_b    = (const float*)d_in[22];
    float* out = (float*)d_out;

    const size_t MB = 1ull << 20;
    char* base = (char*)d_ws;
    float*  x    = (float*)(base);             // 8 MB residual
    ushort* xn   = (ushort*)(base + 8 * MB);   // 4 MB normed bf16
    float*  t2   = (float*)(base + 12 * MB);   // 8 MB
    float*  qb   = (float*)(base + 20 * MB);   // 8 MB   } lifetime: attn
    float*  kb   = (float*)(base + 28 * MB);   // 8 MB   }
    float*  vb   = (float*)(base + 36 * MB);   // 8 MB   }
    ushort* attb = (ushort*)(base + 44 * MB);  // 4 MB   }
    ushort* qhb  = (ushort*)(base + 48 * MB);  // 4 MB   } bf16 [h][L][64]
    ushort* khb  = (ushort*)(base + 52 * MB);  // 4 MB   } bf16 [h][L][64]
    ushort* vtb  = (ushort*)(base + 56 * MB);  // 4 MB   } bf16 [h][64][L]
    float*  z1   = (float*)(base + 20 * MB);   // 26.9 MB, reuses qb.. (attn dead)
    float*  z3   = (float*)(base + 48 * MB);   // 26.9 MB (qh/kh/vt dead)
    ushort* z1b  = (ushort*)(base + 75 * MB);  // 13.5 MB (stride 3296, padded)
    ushort* wbuf = (ushort*)(base + 89 * MB);  // 16.5 MB weight scratch

    const size_t LD = (size_t)Lm * Dm;
    int nLD4 = (int)(LD / 4);

    dim3 gemmD(8, 16);    // N=1024
    dim3 gemmI(26, 16);   // N=3280 (Np=3328)
    dim3 gemmC(63, 16);   // N=8000 (Np=8064) LM chunk

    embed_k<<<Lm, 256, 0, stream>>>(tokens, embed_w, x);

    for (int l = 0; l < NLAYER; ++l) {
        size_t oDD = (size_t)l * Dm * Dm, oD = (size_t)l * Dm;
        size_t oID = (size_t)l * Im * Dm, oI = (size_t)l * Im;
        size_t oH = (size_t)l * HDm;

        rmsnorm_row<<<Lm, 256, 0, stream>>>(x, ln1_w + oD, xn);

        convert_w<<<dim3(4, 1024), 256, 0, stream>>>(wq_w + oDD, wbuf, Dm, Dm, Dm);
        gemm_bf16<<<gemmD, 256, 0, stream>>>(xn, wbuf, wq_b + oD, qb, Dm, Dm, Dm, 0);
        convert_w<<<dim3(4, 1024), 256, 0, stream>>>(wk_w + oDD, wbuf, Dm, Dm, Dm);
        gemm_bf16<<<gemmD, 256, 0, stream>>>(xn, wbuf, wk_b + oD, kb, Dm, Dm, Dm, 0);
        convert_w<<<dim3(4, 1024), 256, 0, stream>>>(wv_w + oDD, wbuf, Dm, Dm, Dm);
        gemm_bf16<<<gemmD, 256, 0, stream>>>(xn, wbuf, wv_b + oD, vb, Dm, Dm, Dm, 0);

        rmsnorm_head_bf16<<<(Lm * Hn) / 4, 256, 0, stream>>>(qb, qn_w + oH, qhb);
        rmsnorm_head_bf16<<<(Lm * Hn) / 4, 256, 0, stream>>>(kb, kn_w + oH, khb);
        vtrans_k<<<dim3(Lm / 64, Hn), 256, 0, stream>>>(vb, vtb);
        attn_mfma<<<dim3(Lm / 64, Hn), 256, 0, stream>>>(qhb, khb, vtb, attb);

        convert_w<<<dim3(4, 1024), 256, 0, stream>>>(wo_w + oDD, wbuf, Dm, Dm, Dm);
        gemm_bf16<<<gemmD, 256, 0, stream>>>(attb, wbuf, wo_b + oD, t2, Dm, Dm, Dm, 0);
        add_k<<<(nLD4 + 255) / 256, 256, 0, stream>>>(x, t2, nLD4);

        rmsnorm_row<<<Lm, 256, 0, stream>>>(x, ln2_w + oD, xn);

        convert_w<<<dim3(4, 3328), 256, 0, stream>>>(w1_w + oID, wbuf, Im, Dm, Dm);
        gemm_bf16<<<gemmI, 256, 0, stream>>>(xn, wbuf, w1_b + oI, z1, Dm, Im, Im, 0);
        convert_w<<<dim3(4, 3328), 256, 0, stream>>>(w3_w + oID, wbuf, Im, Dm, Dm);
        gemm_bf16<<<gemmI, 256, 0, stream>>>(xn, wbuf, w3_b + oI, z3, Dm, Im, Im, 0);
        swiglu_k<<<Lm, 256, 0, stream>>>(z1, z3, z1b);

        convert_w<<<dim3(13, 1024), 256, 0, stream>>>(w2_w + oID, wbuf, Dm, Im, 3296);
        gemm_bf16<<<gemmD, 256, 0, stream>>>(z1b, wbuf, w2_b + oD, t2, 3296, Dm, Dm, 0);
        add_k<<<(nLD4 + 255) / 256, 256, 0, stream>>>(x, t2, nLD4);
    }

    rmsnorm_row<<<Lm, 256, 0, stream>>>(x, lnf_w, xn);
    for (int c = 0; c < 4; ++c) {
        convert_w<<<dim3(4, 8064), 256, 0, stream>>>(lm_w + (size_t)c * 8000 * Dm,
                                                     wbuf, 8000, Dm, Dm);
        gemm_bf16<<<gemmC, 256, 0, stream>>>(xn, wbuf, lm_b + c * 8000,
                                             out + c * 8000, Dm, 8000, Vm, 1);
    }
}

// Round 4
// 2071.310 us; speedup vs baseline: 1.6853x; 1.0886x over previous
//
#include <hip/hip_runtime.h>
#include <hip/hip_bf16.h>
#include <math.h>

#define Dm   1024
#define Hn   16
#define HDm  64
#define Lm   2048
#define Wm   256
#define Im   3280
#define Vm   32000
#define NLAYER 4
#define EPSf 1e-5f
#define QKVN 3072
#define FFN  6560
#define FFNP 6656
#define IP   3328

typedef unsigned short ushort;
typedef __attribute__((ext_vector_type(8))) short bf16x8;
typedef __attribute__((ext_vector_type(4))) float f32x4;

static __device__ __forceinline__ float clamp10k(float x) {
    return fminf(fmaxf(x, -10000.0f), 10000.0f);
}

static __device__ __forceinline__ ushort f2bf(float f) {
    __hip_bfloat16 h = __float2bfloat16(f);
    return *reinterpret_cast<ushort*>(&h);
}

// async global->LDS, 16 bytes per lane; LDS dest = wave-uniform base + lane*16
static __device__ __forceinline__ void gload16(const ushort* g, ushort* l) {
    __builtin_amdgcn_global_load_lds(
        (const __attribute__((address_space(1))) void*)(const void*)g,
        (__attribute__((address_space(3))) void*)(void*)l, 16, 0, 0);
}

// ---------------- embedding gather ----------------
__global__ __launch_bounds__(256) void embed_k(const int* __restrict__ tok,
                                               const float* __restrict__ ew,
                                               float* __restrict__ x) {
    int i = blockIdx.x;
    int t = tok[i];
    const float4* src = (const float4*)(ew + (size_t)t * Dm);
    float4* dst = (float4*)(x + (size_t)i * Dm);
    dst[threadIdx.x] = src[threadIdx.x];
}

// ---------------- RMSNorm over D=1024, bf16 output ----------------
__global__ __launch_bounds__(256) void rmsnorm_row(const float* __restrict__ x,
                                                   const float* __restrict__ w,
                                                   ushort* __restrict__ out) {
    __shared__ float red[256];
    int row = blockIdx.x, tid = threadIdx.x;
    float4 vx = ((const float4*)(x + (size_t)row * Dm))[tid];
    vx.x = clamp10k(vx.x); vx.y = clamp10k(vx.y);
    vx.z = clamp10k(vx.z); vx.w = clamp10k(vx.w);
    float ss = vx.x * vx.x + vx.y * vx.y + vx.z * vx.z + vx.w * vx.w;
    red[tid] = ss;
    __syncthreads();
    for (int s = 128; s > 0; s >>= 1) {
        if (tid < s) red[tid] += red[tid + s];
        __syncthreads();
    }
    float mean = red[0] * (1.0f / Dm);
    float inv = 1.0f / sqrtf(fmaxf(mean, EPSf) + EPSf);
    float4 vw = ((const float4*)w)[tid];
    float o0 = vx.x * inv * vw.x;
    float o1 = vx.y * inv * vw.y;
    float o2 = vx.z * inv * vw.z;
    float o3 = vx.w * inv * vw.w;
    if (!isfinite(o0)) o0 = 0.0f;
    if (!isfinite(o1)) o1 = 0.0f;
    if (!isfinite(o2)) o2 = 0.0f;
    if (!isfinite(o3)) o3 = 0.0f;
    ushort4 o;
    o.x = f2bf(o0); o.y = f2bf(o1); o.z = f2bf(o2); o.w = f2bf(o3);
    ((ushort4*)(out + (size_t)row * Dm))[tid] = o;
}

// ---------------- per-head RMSNorm over hd=64 -> bf16 [h][L][64] ----------------
// input: section of fused qkv fp32 [L][3072]; element (i,h,d) at i*3072 + h*64 + d.
__global__ __launch_bounds__(256) void rmsnorm_head_bf16(const float* __restrict__ qk,
                                                         const float* __restrict__ w,
                                                         ushort* __restrict__ out) {
    int wave = threadIdx.x >> 6, lane = threadIdx.x & 63;
    int r = blockIdx.x * 4 + wave;
    int i = r >> 4, h = r & 15;
    float xv = clamp10k(qk[(size_t)i * QKVN + h * HDm + lane]);
    float ss = xv * xv;
#pragma unroll
    for (int off = 32; off >= 1; off >>= 1) ss += __shfl_xor(ss, off, 64);
    float mean = ss * (1.0f / HDm);
    float inv = 1.0f / sqrtf(fmaxf(mean, EPSf) + EPSf);
    float o = xv * inv * w[lane];
    if (!isfinite(o)) o = 0.0f;
    out[((size_t)h * Lm + i) * HDm + lane] = f2bf(o);
}

// ---------------- V transpose: v-section of qkv fp32 [L][3072] -> vt bf16 [h][64][L] --
__global__ __launch_bounds__(256) void vtrans_k(const float* __restrict__ vb,
                                                ushort* __restrict__ vt) {
    __shared__ ushort tile[64 * 72];   // [d][i], padded stride
    int i0 = blockIdx.x * 64, h = blockIdx.y;
    int t = threadIdx.x;
    int r = t >> 2, q4 = t & 3;        // r = i-row 0..63
    const float4* src = (const float4*)(vb + (size_t)(i0 + r) * QKVN + h * HDm);
#pragma unroll
    for (int k = 0; k < 4; ++k) {
        int c4 = q4 + k * 4;           // float4 index 0..15
        float4 v = src[c4];
        int c = c4 * 4;
        tile[(c + 0) * 72 + r] = f2bf(v.x);
        tile[(c + 1) * 72 + r] = f2bf(v.y);
        tile[(c + 2) * 72 + r] = f2bf(v.z);
        tile[(c + 3) * 72 + r] = f2bf(v.w);
    }
    __syncthreads();
    int d = t >> 2, ch = t & 3;
    uint4 a = *(const uint4*)&tile[d * 72 + ch * 16];
    uint4 b = *(const uint4*)&tile[d * 72 + ch * 16 + 8];
    ushort* dst = vt + ((size_t)(h * HDm + d)) * Lm + i0 + ch * 16;
    *(uint4*)dst = a;
    *(uint4*)(dst + 8) = b;
}

// ---------------- MFMA sliding-window flash attention ----------------
__global__ __launch_bounds__(256) void attn_mfma(const ushort* __restrict__ qh,
                                                 const ushort* __restrict__ kh,
                                                 const ushort* __restrict__ vt,
                                                 ushort* __restrict__ out) {
    __shared__ ushort Ks[32 * 72];     // [key][feat], padded
    __shared__ ushort Vs[64 * 40];     // [feat][key], padded
    __shared__ ushort Pl[4][16 * 40];  // per-wave P [q][key], padded

    const int tid  = threadIdx.x;
    const int wave = tid >> 6;
    const int lane = tid & 63;
    const int l15  = lane & 15;
    const int quad = lane >> 4;
    const int h    = blockIdx.y;
    const int q0   = blockIdx.x * 64;
    const int qw   = q0 + wave * 16;
    const int qmy  = qw + l15;

    const ushort* qbase = qh + ((size_t)h * Lm + qw + l15) * HDm;
    bf16x8 qf0 = *(const bf16x8*)(qbase + quad * 8);
    bf16x8 qf1 = *(const bf16x8*)(qbase + 32 + quad * 8);

    f32x4 o0 = {0.f, 0.f, 0.f, 0.f}, o1 = o0, o2 = o0, o3 = o0;
    // m floor at -1e4: legit scores bounded ~|512|, so max(m, rm) never binds on
    // real data, and fully-masked tiles give p = exp(-1e30 + 1e4) = 0 exactly.
    float m = -1e4f, lsum = 0.0f;

    const int krow = tid >> 3, kch = tid & 7;
    const int vrow = tid >> 2, vch = tid & 3;
    const ushort* kg = kh + ((size_t)h * Lm + krow) * HDm + kch * 8;
    const ushort* vg = vt + ((size_t)(h * HDm + vrow)) * Lm + vch * 8;

    int tlo = q0 - 256; if (tlo < 0) tlo = 0;

    for (int t0 = tlo; t0 < q0 + 64; t0 += 32) {
        __syncthreads();
        *(uint4*)&Ks[krow * 72 + kch * 8] = *(const uint4*)(kg + (size_t)t0 * HDm);
        *(uint4*)&Vs[vrow * 40 + vch * 8] = *(const uint4*)(vg + t0);
        __syncthreads();

        if (t0 <= qw + 15 && t0 + 31 >= qw - 255) {
            bf16x8 k00 = *(const bf16x8*)&Ks[l15 * 72 + quad * 8];
            bf16x8 k01 = *(const bf16x8*)&Ks[l15 * 72 + 32 + quad * 8];
            bf16x8 k10 = *(const bf16x8*)&Ks[(l15 + 16) * 72 + quad * 8];
            bf16x8 k11 = *(const bf16x8*)&Ks[(l15 + 16) * 72 + 32 + quad * 8];
            f32x4 s0 = {0.f, 0.f, 0.f, 0.f}, s1 = s0;
            s0 = __builtin_amdgcn_mfma_f32_16x16x32_bf16(k00, qf0, s0, 0, 0, 0);
            s0 = __builtin_amdgcn_mfma_f32_16x16x32_bf16(k01, qf1, s0, 0, 0, 0);
            s1 = __builtin_amdgcn_mfma_f32_16x16x32_bf16(k10, qf0, s1, 0, 0, 0);
            s1 = __builtin_amdgcn_mfma_f32_16x16x32_bf16(k11, qf1, s1, 0, 0, 0);

            float sv[8];
            bool full = (t0 + 31 <= qw) && (t0 >= qw - 240);
            int jb = t0 + quad * 4;
            if (full) {
#pragma unroll
                for (int r = 0; r < 4; ++r) {
                    sv[r]     = s0[r] * 0.125f;
                    sv[r + 4] = s1[r] * 0.125f;
                }
            } else {
#pragma unroll
                for (int r = 0; r < 4; ++r) {
                    int ja = jb + r, jc = jb + 16 + r;
                    sv[r]     = (ja <= qmy && ja >= qmy - 255) ? s0[r] * 0.125f : -1e30f;
                    sv[r + 4] = (jc <= qmy && jc >= qmy - 255) ? s1[r] * 0.125f : -1e30f;
                }
            }

            float rm = sv[0];
#pragma unroll
            for (int r = 1; r < 8; ++r) rm = fmaxf(rm, sv[r]);
            rm = fmaxf(rm, __shfl_xor(rm, 16));
            rm = fmaxf(rm, __shfl_xor(rm, 32));
            float mn = fmaxf(m, rm);
            float alpha = __expf(m - mn);
            float p[8], ps = 0.f;
#pragma unroll
            for (int r = 0; r < 8; ++r) { p[r] = __expf(sv[r] - mn); ps += p[r]; }
            ps += __shfl_xor(ps, 16);
            ps += __shfl_xor(ps, 32);
            lsum = lsum * alpha + ps;
            m = mn;

            ushort4 pk0, pk1;
            pk0.x = f2bf(p[0]); pk0.y = f2bf(p[1]); pk0.z = f2bf(p[2]); pk0.w = f2bf(p[3]);
            pk1.x = f2bf(p[4]); pk1.y = f2bf(p[5]); pk1.z = f2bf(p[6]); pk1.w = f2bf(p[7]);
            *(ushort4*)&Pl[wave][l15 * 40 + quad * 4]      = pk0;
            *(ushort4*)&Pl[wave][l15 * 40 + 16 + quad * 4] = pk1;
            asm volatile("s_waitcnt lgkmcnt(0)" ::: "memory");
            bf16x8 pa  = *(const bf16x8*)&Pl[wave][l15 * 40 + quad * 8];
            bf16x8 vf0 = *(const bf16x8*)&Vs[l15 * 40 + quad * 8];
            bf16x8 vf1 = *(const bf16x8*)&Vs[(l15 + 16) * 40 + quad * 8];
            bf16x8 vf2 = *(const bf16x8*)&Vs[(l15 + 32) * 40 + quad * 8];
            bf16x8 vf3 = *(const bf16x8*)&Vs[(l15 + 48) * 40 + quad * 8];

            float a0 = __shfl(alpha, quad * 4 + 0);
            float a1 = __shfl(alpha, quad * 4 + 1);
            float a2 = __shfl(alpha, quad * 4 + 2);
            float a3 = __shfl(alpha, quad * 4 + 3);
            o0[0] *= a0; o0[1] *= a1; o0[2] *= a2; o0[3] *= a3;
            o1[0] *= a0; o1[1] *= a1; o1[2] *= a2; o1[3] *= a3;
            o2[0] *= a0; o2[1] *= a1; o2[2] *= a2; o2[3] *= a3;
            o3[0] *= a0; o3[1] *= a1; o3[2] *= a2; o3[3] *= a3;

            o0 = __builtin_amdgcn_mfma_f32_16x16x32_bf16(pa, vf0, o0, 0, 0, 0);
            o1 = __builtin_amdgcn_mfma_f32_16x16x32_bf16(pa, vf1, o1, 0, 0, 0);
            o2 = __builtin_amdgcn_mfma_f32_16x16x32_bf16(pa, vf2, o2, 0, 0, 0);
            o3 = __builtin_amdgcn_mfma_f32_16x16x32_bf16(pa, vf3, o3, 0, 0, 0);
        }
    }

    float linv = 1.0f / lsum;
    ushort* ob = out + (size_t)(qw + quad * 4) * Dm + h * HDm + l15;
#pragma unroll
    for (int r = 0; r < 4; ++r) {
        float li = __shfl(linv, quad * 4 + r);
        size_t off = (size_t)r * Dm;
        ob[off]      = f2bf(o0[r] * li);
        ob[off + 16] = f2bf(o1[r] * li);
        ob[off + 32] = f2bf(o2[r] * li);
        ob[off + 48] = f2bf(o3[r] * li);
    }
}

// ---------------- weight fp32 -> bf16 with zero padding to Np x Kp ----------------
__global__ __launch_bounds__(256) void convert_w(const float* __restrict__ src,
                                                 ushort* __restrict__ dst,
                                                 int N, int K, int Kp) {
    int n = blockIdx.y;
    int k = blockIdx.x * 256 + threadIdx.x;
    if (k >= Kp) return;
    float v = 0.0f;
    if (n < N && k < K) v = src[(size_t)n * K + k];
    dst[(size_t)n * Kp + k] = f2bf(v);
}

// ---------------- concat up to 3 bias vectors (zero-fill past total) --------------
__global__ __launch_bounds__(256) void cat3_k(float* __restrict__ dst,
                                              const float* __restrict__ a, int na,
                                              const float* __restrict__ b, int nb,
                                              const float* __restrict__ c, int nc,
                                              int ntot) {
    int i = blockIdx.x * 256 + threadIdx.x;
    if (i >= ntot) return;
    float v = 0.0f;
    if (i < na) v = a[i];
    else if (i < na + nb) v = b[i - na];
    else if (i < na + nb + nc) v = c[i - na - nb];
    dst[i] = v;
}

// ---------------- bf16 MFMA GEMM: C(2048 x N) = A(2048 x K) @ Wb(Npad x K)^T + bias --
// K mult of 64; tile 128x128, BK=64; 4 waves each 64x64 of 16x16x32 MFMAs.
// res != null: C = res + (A@W^T + bias)   (residual fused)
__global__ __launch_bounds__(256) void gemm_bf16(const ushort* __restrict__ A,
                                                 const ushort* __restrict__ Wb,
                                                 const float* __restrict__ bias,
                                                 const float* __restrict__ res,
                                                 float* __restrict__ C,
                                                 int K, int N, int ldc, int act) {
    __shared__ ushort As[128 * 64];
    __shared__ ushort Bs[128 * 64];
    const int tid = threadIdx.x;
    const int wave = tid >> 6;
    const int lane = tid & 63;
    const int lane15 = lane & 15;
    const int quad = lane >> 4;
    const int rowBlk = blockIdx.y * 128;
    const int colBlk = blockIdx.x * 128;
    const int wm = (wave >> 1) * 64;
    const int wn = (wave & 1) * 64;

    const int srow = lane >> 3;          // 0..7
    const int scol = (lane & 7) * 8;     // bf16 col offset 0..56

    const ushort* aSrc = A + (size_t)(rowBlk + wave * 32 + srow) * K + scol;
    const ushort* bSrc = Wb + (size_t)(colBlk + wave * 32 + srow) * K + scol;
    ushort* aD = &As[(wave * 32) * 64];
    ushort* bD = &Bs[(wave * 32) * 64];

    f32x4 acc[4][4];
#pragma unroll
    for (int i = 0; i < 4; ++i)
#pragma unroll
        for (int j = 0; j < 4; ++j) acc[i][j] = (f32x4){0.f, 0.f, 0.f, 0.f};

    for (int k0 = 0; k0 < K; k0 += 64) {
        __syncthreads();   // previous iteration's reads complete
#pragma unroll
        for (int g = 0; g < 4; ++g) {
            gload16(aSrc + k0 + (size_t)(g * 8) * K, aD + g * 8 * 64);
            gload16(bSrc + k0 + (size_t)(g * 8) * K, bD + g * 8 * 64);
        }
        __syncthreads();   // staging complete

#pragma unroll
        for (int kk = 0; kk < 2; ++kk) {
            bf16x8 a[4], b[4];
#pragma unroll
            for (int im = 0; im < 4; ++im)
                a[im] = *(const bf16x8*)&As[(wm + im * 16 + lane15) * 64 + kk * 32 + quad * 8];
#pragma unroll
            for (int in = 0; in < 4; ++in)
                b[in] = *(const bf16x8*)&Bs[(wn + in * 16 + lane15) * 64 + kk * 32 + quad * 8];
#pragma unroll
            for (int im = 0; im < 4; ++im)
#pragma unroll
                for (int in = 0; in < 4; ++in)
                    acc[im][in] = __builtin_amdgcn_mfma_f32_16x16x32_bf16(
                        a[im], b[in], acc[im][in], 0, 0, 0);
        }
    }

#pragma unroll
    for (int im = 0; im < 4; ++im) {
        int r0 = rowBlk + wm + im * 16 + quad * 4;
#pragma unroll
        for (int in = 0; in < 4; ++in) {
            int c = colBlk + wn + in * 16 + lane15;
            if (c < N) {
                float bia = bias[c];
#pragma unroll
                for (int reg = 0; reg < 4; ++reg) {
                    float v = acc[im][in][reg] + bia;
                    if (act) v = fminf(fmaxf(v, -50.0f), 50.0f);
                    size_t idx = (size_t)(r0 + reg) * ldc + c;
                    if (res) v += res[idx];
                    C[idx] = v;
                }
            }
        }
    }
}

// ---------------- swiglu on fused z13 [L][6656]: z1b[L][3328] = silu(z1)*z3 ---------
__global__ __launch_bounds__(256) void swiglu_k(const float* __restrict__ z13,
                                                ushort* __restrict__ z1b) {
    int row = blockIdx.x, tid = threadIdx.x;
    const float* r = z13 + (size_t)row * FFNP;
    ushort* o = z1b + (size_t)row * IP;
    for (int c = tid; c < IP; c += 256) {
        float v = 0.0f;
        if (c < Im) {
            float x = r[c];
            v = x / (1.0f + expf(-x)) * r[Im + c];
        }
        o[c] = f2bf(v);
    }
}

extern "C" void kernel_launch(void* const* d_in, const int* in_sizes, int n_in,
                              void* d_out, int out_size, void* d_ws, size_t ws_size,
                              hipStream_t stream) {
    const int*   tokens  = (const int*)  d_in[0];
    const float* embed_w = (const float*)d_in[1];
    const float* ln1_w   = (const float*)d_in[2];
    const float* ln2_w   = (const float*)d_in[3];
    const float* wq_w    = (const float*)d_in[4];
    const float* wq_b    = (const float*)d_in[5];
    const float* wk_w    = (const float*)d_in[6];
    const float* wk_b    = (const float*)d_in[7];
    const float* wv_w    = (const float*)d_in[8];
    const float* wv_b    = (const float*)d_in[9];
    const float* wo_w    = (const float*)d_in[10];
    const float* wo_b    = (const float*)d_in[11];
    const float* qn_w    = (const float*)d_in[12];
    const float* kn_w    = (const float*)d_in[13];
    const float* w1_w    = (const float*)d_in[14];
    const float* w1_b    = (const float*)d_in[15];
    const float* w2_w    = (const float*)d_in[16];
    const float* w2_b    = (const float*)d_in[17];
    const float* w3_w    = (const float*)d_in[18];
    const float* w3_b    = (const float*)d_in[19];
    const float* lnf_w   = (const float*)d_in[20];
    const float* lm_w    = (const float*)d_in[21];
    const float* lm_b    = (const float*)d_in[22];
    float* out = (float*)d_out;

    const size_t MB = 1ull << 20;
    char* base = (char*)d_ws;
    float*  x    = (float*)(base);             // 0..8 MB residual fp32
    ushort* xn   = (ushort*)(base + 8 * MB);   // 8..12 normed bf16
    float*  qkvb = (float*)(base + 16 * MB);   // 16..41.2 fused qkv fp32 [L][3072]
    ushort* attb = (ushort*)(base + 42 * MB);  // 42..46 attn out bf16 [L][1024]
    ushort* qhb  = (ushort*)(base + 46 * MB);  // 46..50 bf16 [h][L][64]
    ushort* khb  = (ushort*)(base + 50 * MB);  // 50..54 bf16 [h][L][64]
    ushort* vtb  = (ushort*)(base + 54 * MB);  // 54..58 bf16 [h][64][L]
    float*  z13  = (float*)(base + 16 * MB);   // 16..70.5 fused ffn fp32 [L][6656]
                                               // (reuses qkvb..vtb, attn phase done)
    ushort* z1b  = (ushort*)(base + 72 * MB);  // 72..85.7 bf16 [L][3328]
    ushort* wbuf = (ushort*)(base + 88 * MB);  // 88..104.5 weight scratch
    float*  bqkv = (float*)(base + 106 * MB);  // concat qkv bias (12 KB)
    float*  b13  = (float*)(base + 107 * MB);  // concat w1/w3 bias (26 KB)

    dim3 gemmQKV(24, 16);   // N=3072
    dim3 gemmO(8, 16);      // N=1024
    dim3 gemm13(52, 16);    // N=6560 (pad 6656)
    dim3 gemmC(63, 16);     // N=8000 (pad 8064) LM chunk

    embed_k<<<Lm, 256, 0, stream>>>(tokens, embed_w, x);

    for (int l = 0; l < NLAYER; ++l) {
        size_t oDD = (size_t)l * Dm * Dm, oD = (size_t)l * Dm;
        size_t oID = (size_t)l * Im * Dm, oI = (size_t)l * Im;
        size_t oH = (size_t)l * HDm;

        rmsnorm_row<<<Lm, 256, 0, stream>>>(x, ln1_w + oD, xn);

        cat3_k<<<12, 256, 0, stream>>>(bqkv, wq_b + oD, Dm, wk_b + oD, Dm,
                                       wv_b + oD, Dm, QKVN);
        convert_w<<<dim3(4, 1024), 256, 0, stream>>>(wq_w + oDD, wbuf, Dm, Dm, Dm);
        convert_w<<<dim3(4, 1024), 256, 0, stream>>>(wk_w + oDD,
                                                     wbuf + (size_t)Dm * Dm, Dm, Dm, Dm);
        convert_w<<<dim3(4, 1024), 256, 0, stream>>>(wv_w + oDD,
                                                     wbuf + (size_t)2 * Dm * Dm, Dm, Dm, Dm);
        gemm_bf16<<<gemmQKV, 256, 0, stream>>>(xn, wbuf, bqkv, nullptr, qkvb,
                                               Dm, QKVN, QKVN, 0);

        rmsnorm_head_bf16<<<(Lm * Hn) / 4, 256, 0, stream>>>(qkvb, qn_w + oH, qhb);
        rmsnorm_head_bf16<<<(Lm * Hn) / 4, 256, 0, stream>>>(qkvb + Dm, kn_w + oH, khb);
        vtrans_k<<<dim3(Lm / 64, Hn), 256, 0, stream>>>(qkvb + 2 * Dm, vtb);
        attn_mfma<<<dim3(Lm / 64, Hn), 256, 0, stream>>>(qhb, khb, vtb, attb);

        convert_w<<<dim3(4, 1024), 256, 0, stream>>>(wo_w + oDD, wbuf, Dm, Dm, Dm);
        gemm_bf16<<<gemmO, 256, 0, stream>>>(attb, wbuf, wo_b + oD, x, x,
                                             Dm, Dm, Dm, 0);

        rmsnorm_row<<<Lm, 256, 0, stream>>>(x, ln2_w + oD, xn);

        cat3_k<<<26, 256, 0, stream>>>(b13, w1_b + oI, Im, w3_b + oI, Im,
                                       w1_b + oI, 0, FFNP);
        convert_w<<<dim3(4, 3280), 256, 0, stream>>>(w1_w + oID, wbuf, Im, Dm, Dm);
        convert_w<<<dim3(4, 3280), 256, 0, stream>>>(w3_w + oID,
                                                     wbuf + (size_t)Im * Dm, Im, Dm, Dm);
        convert_w<<<dim3(4, 96), 256, 0, stream>>>(w1_w + oID,
                                                   wbuf + (size_t)FFN * Dm, 0, Dm, Dm);
        gemm_bf16<<<gemm13, 256, 0, stream>>>(xn, wbuf, b13, nullptr, z13,
                                              Dm, FFN, FFNP, 0);
        swiglu_k<<<Lm, 256, 0, stream>>>(z13, z1b);

        convert_w<<<dim3(13, 1024), 256, 0, stream>>>(w2_w + oID, wbuf, Dm, Im, IP);
        gemm_bf16<<<gemmO, 256, 0, stream>>>(z1b, wbuf, w2_b + oD, x, x,
                                             IP, Dm, Dm, 0);
    }

    rmsnorm_row<<<Lm, 256, 0, stream>>>(x, lnf_w, xn);
    for (int c = 0; c < 4; ++c) {
        convert_w<<<dim3(4, 8064), 256, 0, stream>>>(lm_w + (size_t)c * 8000 * Dm,
                                                     wbuf, 8000, Dm, Dm);
        gemm_bf16<<<gemmC, 256, 0, stream>>>(xn, wbuf, lm_b + c * 8000, nullptr,
                                             out + c * 8000, Dm, 8000, Vm, 1);
    }
}